// Round 11
// baseline (185.664 us; speedup 1.0000x reference)
//
#include <hip/hip_runtime.h>
#include <math.h>

#define N_SAMPLES 2048
#define E_EDGES   4096
#define NSPLIT    64            // 32 rows per partial slice
#define SPB       4             // samples per block in phase C
#define NBLK      512

// Hand-rolled all-resident grid barrier (512 blocks = 2/CU, co-resident by
// construction). Release: syncthreads drains stores to L2, threadfence +
// agent-scope acq_rel RMW writes back L2. Acquire: agent-scope load + fence
// invalidates stale L2/L1 before reading other XCDs' data.
__device__ __forceinline__ void grid_barrier(int* ctr, int expected) {
    __syncthreads();
    if (threadIdx.x == 0) {
        __threadfence();
        __hip_atomic_fetch_add(ctr, 1, __ATOMIC_ACQ_REL, __HIP_MEMORY_SCOPE_AGENT);
        while (__hip_atomic_load(ctr, __ATOMIC_ACQUIRE, __HIP_MEMORY_SCOPE_AGENT)
               < expected) {
            __builtin_amdgcn_s_sleep(2);
        }
        __threadfence();
    }
    __syncthreads();
}

// ============================================================================
// Fused kernel: 512 blocks x 256 threads (2 blocks/CU, all resident).
//  Phase A: split-K partials of bo = Ro^T X, bi = Ri^T X
//  Phase B: reduce partials -> boT[d][e] = e[e]*bo[e][d]  (blocks 0..127)
//  Phase C: SPB=4 coalesced mi/mo dots + TTN Bloch contraction
// ============================================================================
__global__ __launch_bounds__(256, 2)
void k_fused(const float* __restrict__ Ri,
             const float* __restrict__ Ro,
             const float* __restrict__ X,
             const float* __restrict__ ev,
             const float* __restrict__ th,
             float* __restrict__ pbo,
             float* __restrict__ pbi,
             float* __restrict__ boT,
             float* __restrict__ biT,
             int*   __restrict__ sync,
             float* __restrict__ out) {
    __shared__ float comb[128][33];           // phase A combine (padded)
    __shared__ float redM[4][SPB][8];         // phase C reduce
    __shared__ float R[22][9];                // Bloch rotations (theta only)
    __shared__ float sM[SPB][12], cM[SPB][12];

    const int b = blockIdx.x;     // 0..511
    const int t = threadIdx.x;    // 0..255

    // ---- Bloch rotation matrices for all 22 live u3 gates ----
    if (t < 22) {
        float T = th[3 * t], P = th[3 * t + 1], L = th[3 * t + 2];
        float st, ct, sp, cp, sl, cl;
        sincosf(T, &st, &ct);
        sincosf(P, &sp, &cp);
        sincosf(L, &sl, &cl);
        R[t][0] =  cp * ct * cl - sp * sl;
        R[t][1] = -cp * ct * sl - sp * cl;
        R[t][2] =  cp * st;
        R[t][3] =  sp * ct * cl + cp * sl;
        R[t][4] = -sp * ct * sl + cp * cl;
        R[t][5] =  sp * st;
        R[t][6] = -st * cl;
        R[t][7] =  st * sl;
        R[t][8] =  ct;
    }

    // ======================= Phase A: partial GEMM ==========================
    {
        const int ec   = b & 7;           // 0..7  (128 float4-col chunk)
        const int ns   = b >> 3;          // 0..63 (32-row chunk)
        const int col  = t & 127;
        const int half = t >> 7;
        const int v    = ec * 128 + col;  // global float4 col (0..1023)

        const float4* Ri4 = reinterpret_cast<const float4*>(Ri);
        const float4* Ro4 = reinterpret_cast<const float4*>(Ro);
        const float4* X4  = reinterpret_cast<const float4*>(X);

        float abo[4][4], abi[4][4];
#pragma unroll
        for (int c = 0; c < 4; ++c)
#pragma unroll
            for (int d = 0; d < 4; ++d) { abo[c][d] = 0.f; abi[c][d] = 0.f; }

        const int n0 = ns * 32 + half * 16;
#pragma unroll 4
        for (int n = n0; n < n0 + 16; ++n) {
            float4 xv = X4[n];
            float4 ro = Ro4[(size_t)n * 1024 + v];
            float4 ri = Ri4[(size_t)n * 1024 + v];
            float xs[4]  = {xv.x, xv.y, xv.z, xv.w};
            float ros[4] = {ro.x, ro.y, ro.z, ro.w};
            float ris[4] = {ri.x, ri.y, ri.z, ri.w};
#pragma unroll
            for (int c = 0; c < 4; ++c)
#pragma unroll
                for (int d = 0; d < 4; ++d) {
                    abo[c][d] += ros[c] * xs[d];
                    abi[c][d] += ris[c] * xs[d];
                }
        }

        if (half) {
#pragma unroll
            for (int c = 0; c < 4; ++c)
#pragma unroll
                for (int d = 0; d < 4; ++d) {
                    comb[col][c * 4 + d]      = abo[c][d];
                    comb[col][16 + c * 4 + d] = abi[c][d];
                }
        }
        __syncthreads();
        if (!half) {
            float4* pbo4 = reinterpret_cast<float4*>(pbo);
            float4* pbi4 = reinterpret_cast<float4*>(pbi);
#pragma unroll
            for (int c = 0; c < 4; ++c) {
#pragma unroll
                for (int d = 0; d < 4; ++d) {
                    abo[c][d] += comb[col][c * 4 + d];
                    abi[c][d] += comb[col][16 + c * 4 + d];
                }
                size_t idx = (size_t)ns * E_EDGES + 4 * (size_t)v + c;
                pbo4[idx] = make_float4(abo[c][0], abo[c][1], abo[c][2], abo[c][3]);
                pbi4[idx] = make_float4(abi[c][0], abi[c][1], abi[c][2], abi[c][3]);
            }
        }
    }

    grid_barrier(sync + 0, NBLK);

    // ======================= Phase B: reduce + transpose ====================
    {
        const int gid = b * 256 + t;          // active < 32768 (blocks 0..127)
        if (gid < 32768) {
            const int q   = gid & 3;
            const int e   = (gid >> 2) & 4095;
            const int mat = gid >> 14;        // 0 = bo, 1 = bi
            const float4* src = reinterpret_cast<const float4*>(mat ? pbi : pbo);
            float*        dst = mat ? biT : boT;

            float s0 = 0.f, s1 = 0.f, s2 = 0.f, s3 = 0.f;
#pragma unroll 4
            for (int ns = q * 16; ns < q * 16 + 16; ++ns) {
                float4 a = src[(size_t)ns * E_EDGES + e];
                s0 += a.x; s1 += a.y; s2 += a.z; s3 += a.w;
            }
            s0 += __shfl_xor(s0, 1); s0 += __shfl_xor(s0, 2);
            s1 += __shfl_xor(s1, 1); s1 += __shfl_xor(s1, 2);
            s2 += __shfl_xor(s2, 1); s2 += __shfl_xor(s2, 2);
            s3 += __shfl_xor(s3, 1); s3 += __shfl_xor(s3, 2);
            if (q == 0) {
                const float w = ev[e];
                dst[0 * E_EDGES + e] = w * s0;
                dst[1 * E_EDGES + e] = w * s1;
                dst[2 * E_EDGES + e] = w * s2;
                dst[3 * E_EDGES + e] = w * s3;
            }
        }
    }

    grid_barrier(sync + 16, NBLK);

    // ======================= Phase C: mi/mo + TTN ===========================
    const int n0   = b * SPB;
    const int lane = t & 63;
    const int wv   = t >> 6;

    float accf[SPB][8];
#pragma unroll
    for (int s = 0; s < SPB; ++s)
#pragma unroll
        for (int j = 0; j < 8; ++j) accf[s][j] = 0.f;

    const float4* Ri4s[SPB];
    const float4* Ro4s[SPB];
#pragma unroll
    for (int s = 0; s < SPB; ++s) {
        Ri4s[s] = reinterpret_cast<const float4*>(Ri + (size_t)(n0 + s) * E_EDGES);
        Ro4s[s] = reinterpret_cast<const float4*>(Ro + (size_t)(n0 + s) * E_EDGES);
    }
    const float4* BO0 = reinterpret_cast<const float4*>(boT);
    const float4* BO1 = reinterpret_cast<const float4*>(boT + E_EDGES);
    const float4* BO2 = reinterpret_cast<const float4*>(boT + 2 * E_EDGES);
    const float4* BO3 = reinterpret_cast<const float4*>(boT + 3 * E_EDGES);
    const float4* BI0 = reinterpret_cast<const float4*>(biT);
    const float4* BI1 = reinterpret_cast<const float4*>(biT + E_EDGES);
    const float4* BI2 = reinterpret_cast<const float4*>(biT + 2 * E_EDGES);
    const float4* BI3 = reinterpret_cast<const float4*>(biT + 3 * E_EDGES);

#pragma unroll
    for (int k = 0; k < 4; ++k) {
        const int v = t + 256 * k;
        const float4 o0 = BO0[v], o1 = BO1[v], o2 = BO2[v], o3 = BO3[v];
        const float4 i0 = BI0[v], i1 = BI1[v], i2 = BI2[v], i3 = BI3[v];
#pragma unroll
        for (int s = 0; s < SPB; ++s) {
            const float4 ri = Ri4s[s][v];
            const float4 ro = Ro4s[s][v];
            accf[s][0] += ri.x * o0.x + ri.y * o0.y + ri.z * o0.z + ri.w * o0.w;
            accf[s][1] += ri.x * o1.x + ri.y * o1.y + ri.z * o1.z + ri.w * o1.w;
            accf[s][2] += ri.x * o2.x + ri.y * o2.y + ri.z * o2.z + ri.w * o2.w;
            accf[s][3] += ri.x * o3.x + ri.y * o3.y + ri.z * o3.z + ri.w * o3.w;
            accf[s][4] += ro.x * i0.x + ro.y * i0.y + ro.z * i0.z + ro.w * i0.w;
            accf[s][5] += ro.x * i1.x + ro.y * i1.y + ro.z * i1.z + ro.w * i1.w;
            accf[s][6] += ro.x * i2.x + ro.y * i2.y + ro.z * i2.z + ro.w * i2.w;
            accf[s][7] += ro.x * i3.x + ro.y * i3.y + ro.z * i3.z + ro.w * i3.w;
        }
    }

    // in-wave butterfly reduce in fp32; double only for final combine + sincos
#pragma unroll
    for (int off = 32; off >= 1; off >>= 1)
#pragma unroll
        for (int s = 0; s < SPB; ++s)
#pragma unroll
            for (int j = 0; j < 8; ++j)
                accf[s][j] += __shfl_xor(accf[s][j], off);
    if (lane == 0)
#pragma unroll
        for (int s = 0; s < SPB; ++s)
#pragma unroll
            for (int j = 0; j < 8; ++j) redM[wv][s][j] = accf[s][j];
    __syncthreads();

    if (t < 12 * SPB) {
        const int s = t / 12, w = t % 12;
        double Mw = (w < 8)
            ? ((double)redM[0][s][w] + (double)redM[1][s][w] +
               (double)redM[2][s][w] + (double)redM[3][s][w])
            : (double)X[(n0 + s) * 4 + (w - 8)];
        double sv, cv;
        sincos(Mw, &sv, &cv);   // double: M can be O(1000) rad
        sM[s][w] = (float)sv; cM[s][w] = (float)cv;
    }
    __syncthreads();

    if (t < SPB) {
        const float* sMv = sM[t];
        const float* cMv = cM[t];
        auto iz = [&](int g) -> float {
            return R[g][6] * sMv[g] + R[g][8] * cMv[g];
        };
        auto ivec = [&](int g, float& x, float& y, float& z) {
            x = R[g][0] * sMv[g] + R[g][2] * cMv[g];
            y = R[g][3] * sMv[g] + R[g][5] * cMv[g];
            z = R[g][6] * sMv[g] + R[g][8] * cMv[g];
        };
        auto rot = [&](int g, float& x, float& y, float& z) {
            float nx = R[g][0] * x + R[g][1] * y + R[g][2] * z;
            float ny = R[g][3] * x + R[g][4] * y + R[g][5] * z;
            float nz = R[g][6] * x + R[g][7] * y + R[g][8] * z;
            x = nx; y = ny; z = nz;
        };

        const float z0  = iz(0),  z3  = iz(3), z4 = iz(4);
        const float z7  = iz(7),  z8  = iz(8), z11 = iz(11);

        float x1, y1, z1;  ivec(1, x1, y1, z1);                // w1
        y1 *= z0;  z1 *= z0;          rot(12, x1, y1, z1);     // cx(0,1), u3@36

        float x2, y2, z2;  ivec(2, x2, y2, z2);                // w2
        y2 *= z3;  z2 *= z3;          rot(13, x2, y2, z2);     // cx(3,2), u3@39
        y2 *= z1;  z2 *= z1;          rot(18, x2, y2, z2);     // cx(1,2), u3@54

        float x6, y6, z6;  ivec(6, x6, y6, z6);                // w6
        y6 *= z7;  z6 *= z7;          rot(15, x6, y6, z6);     // cx(7,6), u3@45

        float x5, y5, z5;  ivec(5, x5, y5, z5);                // w5
        y5 *= z4;  z5 *= z4;          rot(14, x5, y5, z5);     // cx(4,5), u3@42
        y5 *= z6;  z5 *= z6;          rot(19, x5, y5, z5);     // cx(6,5), u3@57
        y5 *= z2;  z5 *= z2;          rot(20, x5, y5, z5);     // cx(2,5), u3@60

        float xA, yA, zA;  ivec(10, xA, yA, zA);               // w10
        yA *= z11; zA *= z11;         rot(17, xA, yA, zA);     // cx(11,10), u3@51

        float x9, y9, z9;  ivec(9, x9, y9, z9);                // w9
        y9 *= z8;  z9 *= z8;          rot(16, x9, y9, z9);     // cx(8,9), u3@48
        y9 *= zA;  z9 *= zA;          rot(21, x9, y9, z9);     // cx(10,9), u3@63
        z9 *= z5;                                              // cx(5,9)

        out[n0 + t] = (float)(3.14159265358979323846 * (1.0 - (double)z9));
    }
}

extern "C" void kernel_launch(void* const* d_in, const int* in_sizes, int n_in,
                              void* d_out, int out_size, void* d_ws, size_t ws_size,
                              hipStream_t stream) {
    (void)in_sizes; (void)n_in; (void)out_size; (void)ws_size;
    const float* X  = (const float*)d_in[0];
    const float* ev = (const float*)d_in[1];
    const float* Ri = (const float*)d_in[2];
    const float* Ro = (const float*)d_in[3];
    const float* th = (const float*)d_in[4];
    float* out = (float*)d_out;

    float* pbo = (float*)d_ws;                              // [NSPLIT][4096][4]
    float* pbi = pbo + (size_t)NSPLIT * E_EDGES * 4;        // [NSPLIT][4096][4]
    float* boT = pbi + (size_t)NSPLIT * E_EDGES * 4;        // [4][4096]
    float* biT = boT + (size_t)4 * E_EDGES;                 // [4][4096]
    int*   syn = (int*)(biT + (size_t)4 * E_EDGES);         // 2 counters, padded

    hipMemsetAsync(syn, 0, 128, stream);   // graph-capturable memset node
    hipLaunchKernelGGL(k_fused, dim3(NBLK), dim3(256), 0, stream,
                       Ri, Ro, X, ev, th, pbo, pbi, boT, biT, syn, out);
}

// Round 12
// 63.366 us; speedup vs baseline: 2.9300x; 2.9300x over previous
//
#include <hip/hip_runtime.h>
#include <math.h>

#define N_SAMPLES 2048
#define E_EDGES   4096
#define NSPLIT    64            // 32 rows per partial slice
#define SPB       4             // samples per block in k_sim

// ---------------- Kernel A: bo/bi via block-reduce + atomicAdd --------------
// grid (8, 64) = 512 blocks. Block: 128 float4-cols x 32 rows, rows split
// 2-way across thread halves, combined in padded LDS, then ONE atomicAdd per
// (d, e) per block straight into the transposed, e-weighted boT/biT:
//   boT[d][e] += e[e] * sum_{n in slice} Ro[n][e] * X[n][d]
// Contention: 64 adds/address over 32K addresses; lanes stride-4 (no wave
// conflicts). Kills the pbo/pbi round-trip and the k_reduce kernel.
__global__ __launch_bounds__(256) void k_partial(const float* __restrict__ Ri,
                                                 const float* __restrict__ Ro,
                                                 const float* __restrict__ X,
                                                 const float* __restrict__ ev,
                                                 float* __restrict__ boT,
                                                 float* __restrict__ biT) {
    __shared__ float comb[128][33];   // padded: conflict-free

    const int ec   = blockIdx.x;      // 0..7  (128 float4-col chunk)
    const int ns   = blockIdx.y;      // 0..63 (32-row chunk)
    const int t    = threadIdx.x;
    const int col  = t & 127;         // local float4 col
    const int half = t >> 7;          // 0/1 row-half
    const int v    = ec * 128 + col;  // global float4 col (0..1023)

    const float4* Ri4 = reinterpret_cast<const float4*>(Ri);
    const float4* Ro4 = reinterpret_cast<const float4*>(Ro);
    const float4* X4  = reinterpret_cast<const float4*>(X);
    const float4* EV4 = reinterpret_cast<const float4*>(ev);

    float abo[4][4], abi[4][4];
#pragma unroll
    for (int c = 0; c < 4; ++c)
#pragma unroll
        for (int d = 0; d < 4; ++d) { abo[c][d] = 0.f; abi[c][d] = 0.f; }

    const int n0 = ns * 32 + half * 16;
#pragma unroll 4
    for (int n = n0; n < n0 + 16; ++n) {
        float4 xv = X4[n];
        float4 ro = Ro4[(size_t)n * 1024 + v];
        float4 ri = Ri4[(size_t)n * 1024 + v];
        float xs[4]  = {xv.x, xv.y, xv.z, xv.w};
        float ros[4] = {ro.x, ro.y, ro.z, ro.w};
        float ris[4] = {ri.x, ri.y, ri.z, ri.w};
#pragma unroll
        for (int c = 0; c < 4; ++c)
#pragma unroll
            for (int d = 0; d < 4; ++d) {
                abo[c][d] += ros[c] * xs[d];
                abi[c][d] += ris[c] * xs[d];
            }
    }

    if (half) {
#pragma unroll
        for (int c = 0; c < 4; ++c)
#pragma unroll
            for (int d = 0; d < 4; ++d) {
                comb[col][c * 4 + d]      = abo[c][d];
                comb[col][16 + c * 4 + d] = abi[c][d];
            }
    }
    __syncthreads();
    if (!half) {
        float4 e4 = EV4[v];
        float ee[4] = {e4.x, e4.y, e4.z, e4.w};
#pragma unroll
        for (int c = 0; c < 4; ++c) {
            const int e = 4 * v + c;
#pragma unroll
            for (int d = 0; d < 4; ++d) {
                float vo = (abo[c][d] + comb[col][c * 4 + d])      * ee[c];
                float vi = (abi[c][d] + comb[col][16 + c * 4 + d]) * ee[c];
                atomicAdd(&boT[d * E_EDGES + e], vo);
                atomicAdd(&biT[d * E_EDGES + e], vi);
            }
        }
    }
}

// ============================================================================
// Kernel C: TTN Bloch contraction, SPB=4 samples/block, fp32 wave butterfly
// (double only for the final 4-wave combine + sincos). Identical to R10.
// mi[n][d] = sum_e Ri[n][e]*boT[d][e];  mo[n][d] = sum_e Ro[n][e]*biT[d][e]
// ============================================================================
__global__ __launch_bounds__(256) void k_sim(const float* __restrict__ Ri,
                                             const float* __restrict__ Ro,
                                             const float* __restrict__ X,
                                             const float* __restrict__ th,
                                             const float* __restrict__ boT,
                                             const float* __restrict__ biT,
                                             float* __restrict__ out) {
    __shared__ float  redM[4][SPB][8];
    __shared__ float  R[22][9];     // gate g (theta offset 3g) -> 3x3 Bloch rot
    __shared__ float  sM[SPB][12], cM[SPB][12];

    const int n0   = blockIdx.x * SPB;
    const int t    = threadIdx.x;   // 0..255
    const int lane = t & 63;
    const int wv   = t >> 6;

    // ---- Bloch rotation matrices for all 22 live u3 gates (t < 22) ----
    if (t < 22) {
        float T = th[3 * t], P = th[3 * t + 1], L = th[3 * t + 2];
        float st, ct, sp, cp, sl, cl;
        sincosf(T, &st, &ct);
        sincosf(P, &sp, &cp);
        sincosf(L, &sl, &cl);
        R[t][0] =  cp * ct * cl - sp * sl;
        R[t][1] = -cp * ct * sl - sp * cl;
        R[t][2] =  cp * st;
        R[t][3] =  sp * ct * cl + cp * sl;
        R[t][4] = -sp * ct * sl + cp * cl;
        R[t][5] =  sp * st;
        R[t][6] = -st * cl;
        R[t][7] =  st * sl;
        R[t][8] =  ct;
    }

    // ---- per-thread fp32 partials of mi/mo for SPB samples (coalesced) ----
    float accf[SPB][8];
#pragma unroll
    for (int s = 0; s < SPB; ++s)
#pragma unroll
        for (int j = 0; j < 8; ++j) accf[s][j] = 0.f;

    const float4* Ri4s[SPB];
    const float4* Ro4s[SPB];
#pragma unroll
    for (int s = 0; s < SPB; ++s) {
        Ri4s[s] = reinterpret_cast<const float4*>(Ri + (size_t)(n0 + s) * E_EDGES);
        Ro4s[s] = reinterpret_cast<const float4*>(Ro + (size_t)(n0 + s) * E_EDGES);
    }
    const float4* BO0 = reinterpret_cast<const float4*>(boT);
    const float4* BO1 = reinterpret_cast<const float4*>(boT + E_EDGES);
    const float4* BO2 = reinterpret_cast<const float4*>(boT + 2 * E_EDGES);
    const float4* BO3 = reinterpret_cast<const float4*>(boT + 3 * E_EDGES);
    const float4* BI0 = reinterpret_cast<const float4*>(biT);
    const float4* BI1 = reinterpret_cast<const float4*>(biT + E_EDGES);
    const float4* BI2 = reinterpret_cast<const float4*>(biT + 2 * E_EDGES);
    const float4* BI3 = reinterpret_cast<const float4*>(biT + 3 * E_EDGES);

#pragma unroll
    for (int k = 0; k < 4; ++k) {
        const int v = t + 256 * k;
        const float4 o0 = BO0[v], o1 = BO1[v], o2 = BO2[v], o3 = BO3[v];
        const float4 i0 = BI0[v], i1 = BI1[v], i2 = BI2[v], i3 = BI3[v];
#pragma unroll
        for (int s = 0; s < SPB; ++s) {
            const float4 ri = Ri4s[s][v];
            const float4 ro = Ro4s[s][v];
            accf[s][0] += ri.x * o0.x + ri.y * o0.y + ri.z * o0.z + ri.w * o0.w;
            accf[s][1] += ri.x * o1.x + ri.y * o1.y + ri.z * o1.z + ri.w * o1.w;
            accf[s][2] += ri.x * o2.x + ri.y * o2.y + ri.z * o2.z + ri.w * o2.w;
            accf[s][3] += ri.x * o3.x + ri.y * o3.y + ri.z * o3.z + ri.w * o3.w;
            accf[s][4] += ro.x * i0.x + ro.y * i0.y + ro.z * i0.z + ro.w * i0.w;
            accf[s][5] += ro.x * i1.x + ro.y * i1.y + ro.z * i1.z + ro.w * i1.w;
            accf[s][6] += ro.x * i2.x + ro.y * i2.y + ro.z * i2.z + ro.w * i2.w;
            accf[s][7] += ro.x * i3.x + ro.y * i3.y + ro.z * i3.z + ro.w * i3.w;
        }
    }

    // in-wave butterfly reduce in fp32; double only for final combine + sincos
#pragma unroll
    for (int off = 32; off >= 1; off >>= 1)
#pragma unroll
        for (int s = 0; s < SPB; ++s)
#pragma unroll
            for (int j = 0; j < 8; ++j)
                accf[s][j] += __shfl_xor(accf[s][j], off);
    if (lane == 0)
#pragma unroll
        for (int s = 0; s < SPB; ++s)
#pragma unroll
            for (int j = 0; j < 8; ++j) redM[wv][s][j] = accf[s][j];
    __syncthreads();

    // ---- M angles: double sincos, threads 0..47 -> (sample, wire) ----
    if (t < 12 * SPB) {
        const int s = t / 12, w = t % 12;
        double Mw = (w < 8)
            ? ((double)redM[0][s][w] + (double)redM[1][s][w] +
               (double)redM[2][s][w] + (double)redM[3][s][w])
            : (double)X[(n0 + s) * 4 + (w - 8)];
        double sv, cv;
        sincos(Mw, &sv, &cv);   // double: M can be O(1000) rad
        sM[s][w] = (float)sv; cM[s][w] = (float)cv;
    }
    __syncthreads();

    // ---- TTN Bloch-vector contraction: thread s handles sample s ----
    if (t < SPB) {
        const float* sMv = sM[t];
        const float* cMv = cM[t];
        auto iz = [&](int g) -> float {
            return R[g][6] * sMv[g] + R[g][8] * cMv[g];
        };
        auto ivec = [&](int g, float& x, float& y, float& z) {
            x = R[g][0] * sMv[g] + R[g][2] * cMv[g];
            y = R[g][3] * sMv[g] + R[g][5] * cMv[g];
            z = R[g][6] * sMv[g] + R[g][8] * cMv[g];
        };
        auto rot = [&](int g, float& x, float& y, float& z) {
            float nx = R[g][0] * x + R[g][1] * y + R[g][2] * z;
            float ny = R[g][3] * x + R[g][4] * y + R[g][5] * z;
            float nz = R[g][6] * x + R[g][7] * y + R[g][8] * z;
            x = nx; y = ny; z = nz;
        };

        const float z0  = iz(0),  z3  = iz(3), z4 = iz(4);
        const float z7  = iz(7),  z8  = iz(8), z11 = iz(11);

        float x1, y1, z1;  ivec(1, x1, y1, z1);                // w1
        y1 *= z0;  z1 *= z0;          rot(12, x1, y1, z1);     // cx(0,1), u3@36

        float x2, y2, z2;  ivec(2, x2, y2, z2);                // w2
        y2 *= z3;  z2 *= z3;          rot(13, x2, y2, z2);     // cx(3,2), u3@39
        y2 *= z1;  z2 *= z1;          rot(18, x2, y2, z2);     // cx(1,2), u3@54

        float x6, y6, z6;  ivec(6, x6, y6, z6);                // w6
        y6 *= z7;  z6 *= z7;          rot(15, x6, y6, z6);     // cx(7,6), u3@45

        float x5, y5, z5;  ivec(5, x5, y5, z5);                // w5
        y5 *= z4;  z5 *= z4;          rot(14, x5, y5, z5);     // cx(4,5), u3@42
        y5 *= z6;  z5 *= z6;          rot(19, x5, y5, z5);     // cx(6,5), u3@57
        y5 *= z2;  z5 *= z2;          rot(20, x5, y5, z5);     // cx(2,5), u3@60

        float xA, yA, zA;  ivec(10, xA, yA, zA);               // w10
        yA *= z11; zA *= z11;         rot(17, xA, yA, zA);     // cx(11,10), u3@51

        float x9, y9, z9;  ivec(9, x9, y9, z9);                // w9
        y9 *= z8;  z9 *= z8;          rot(16, x9, y9, z9);     // cx(8,9), u3@48
        y9 *= zA;  z9 *= zA;          rot(21, x9, y9, z9);     // cx(10,9), u3@63
        z9 *= z5;                                              // cx(5,9)

        out[n0 + t] = (float)(3.14159265358979323846 * (1.0 - (double)z9));
    }
}

extern "C" void kernel_launch(void* const* d_in, const int* in_sizes, int n_in,
                              void* d_out, int out_size, void* d_ws, size_t ws_size,
                              hipStream_t stream) {
    (void)in_sizes; (void)n_in; (void)out_size; (void)ws_size;
    const float* X  = (const float*)d_in[0];
    const float* ev = (const float*)d_in[1];
    const float* Ri = (const float*)d_in[2];
    const float* Ro = (const float*)d_in[3];
    const float* th = (const float*)d_in[4];
    float* out = (float*)d_out;

    float* boT = (float*)d_ws;                 // [4][4096]
    float* biT = boT + (size_t)4 * E_EDGES;    // [4][4096]

    // zero the atomic accumulators (graph-capturable memset node)
    hipMemsetAsync(boT, 0, 2 * 4 * E_EDGES * sizeof(float), stream);
    hipLaunchKernelGGL(k_partial, dim3(8, NSPLIT), dim3(256), 0, stream,
                       Ri, Ro, X, ev, boT, biT);
    hipLaunchKernelGGL(k_sim, dim3(N_SAMPLES / SPB), dim3(256), 0, stream,
                       Ri, Ro, X, th, boT, biT, out);
}

// Round 13
// 43.930 us; speedup vs baseline: 4.2263x; 1.4424x over previous
//
#include <hip/hip_runtime.h>
#include <math.h>

#define N_SAMPLES 2048
#define E_EDGES   4096
#define NSPLIT    128           // 16 rows per partial slice (8 per half)
#define SPB       4             // samples per block in k_sim

// ---------------- Kernel A: split-K partials of bo = Ro^T X, bi = Ri^T X ----
// grid (8, 128) = 1024 blocks (4/CU, 4 waves/SIMD: max outstanding loads on
// the HBM-bound pass). Block: 128 float4-cols x 16 rows, rows split 2-way
// across thread halves, combined through padded LDS. NORMAL stores (R9: nt
// stores force an HBM round-trip, -56%; R12: atomics ping-pong lines, -63%).
__global__ __launch_bounds__(256) void k_partial(const float* __restrict__ Ri,
                                                 const float* __restrict__ Ro,
                                                 const float* __restrict__ X,
                                                 float* __restrict__ pbo,
                                                 float* __restrict__ pbi) {
    __shared__ float comb[128][33];   // padded: conflict-free

    const int ec   = blockIdx.x;      // 0..7   (128 float4-col chunk)
    const int ns   = blockIdx.y;      // 0..127 (16-row chunk)
    const int t    = threadIdx.x;
    const int col  = t & 127;         // local float4 col
    const int half = t >> 7;          // 0/1 row-half
    const int v    = ec * 128 + col;  // global float4 col (0..1023)

    const float4* Ri4 = reinterpret_cast<const float4*>(Ri);
    const float4* Ro4 = reinterpret_cast<const float4*>(Ro);
    const float4* X4  = reinterpret_cast<const float4*>(X);

    float abo[4][4], abi[4][4];
#pragma unroll
    for (int c = 0; c < 4; ++c)
#pragma unroll
        for (int d = 0; d < 4; ++d) { abo[c][d] = 0.f; abi[c][d] = 0.f; }

    const int n0 = ns * 16 + half * 8;
#pragma unroll
    for (int n = n0; n < n0 + 8; ++n) {
        float4 xv = X4[n];
        float4 ro = Ro4[(size_t)n * 1024 + v];
        float4 ri = Ri4[(size_t)n * 1024 + v];
        float xs[4]  = {xv.x, xv.y, xv.z, xv.w};
        float ros[4] = {ro.x, ro.y, ro.z, ro.w};
        float ris[4] = {ri.x, ri.y, ri.z, ri.w};
#pragma unroll
        for (int c = 0; c < 4; ++c)
#pragma unroll
            for (int d = 0; d < 4; ++d) {
                abo[c][d] += ros[c] * xs[d];
                abi[c][d] += ris[c] * xs[d];
            }
    }

    if (half) {
#pragma unroll
        for (int c = 0; c < 4; ++c)
#pragma unroll
            for (int d = 0; d < 4; ++d) {
                comb[col][c * 4 + d]      = abo[c][d];
                comb[col][16 + c * 4 + d] = abi[c][d];
            }
    }
    __syncthreads();
    if (!half) {
        float4* pbo4 = reinterpret_cast<float4*>(pbo);
        float4* pbi4 = reinterpret_cast<float4*>(pbi);
#pragma unroll
        for (int c = 0; c < 4; ++c) {
#pragma unroll
            for (int d = 0; d < 4; ++d) {
                abo[c][d] += comb[col][c * 4 + d];
                abi[c][d] += comb[col][16 + c * 4 + d];
            }
            size_t idx = (size_t)ns * E_EDGES + 4 * (size_t)v + c;
            pbo4[idx] = make_float4(abo[c][0], abo[c][1], abo[c][2], abo[c][3]);
            pbi4[idx] = make_float4(abi[c][0], abi[c][1], abi[c][2], abi[c][3]);
        }
    }
}

// ---------------- Kernel B: reduce partials -> boT, biT (d-major, e-folded) -
// boT[d][e] = e[e] * bo[e][d].  4-way ns-split per (mat,e): thread (mat,e,q)
// sums 32 slices; 2-step shfl_xor combine; q==0 lane writes.
// grid: 2 mats * 4096 e * 4 q / 256 = 128 blocks.
__global__ __launch_bounds__(256) void k_reduce(const float* __restrict__ pbo,
                                                const float* __restrict__ pbi,
                                                const float* __restrict__ ev,
                                                float* __restrict__ boT,
                                                float* __restrict__ biT) {
    const int gid = blockIdx.x * 256 + threadIdx.x;   // 0..32767
    const int q   = gid & 3;
    const int e   = (gid >> 2) & 4095;
    const int mat = gid >> 14;                        // 0 = bo, 1 = bi
    const float4* src = reinterpret_cast<const float4*>(mat ? pbi : pbo);
    float*        dst = mat ? biT : boT;

    float s0 = 0.f, s1 = 0.f, s2 = 0.f, s3 = 0.f;
#pragma unroll 4
    for (int ns = q * 32; ns < q * 32 + 32; ++ns) {
        float4 a = src[(size_t)ns * E_EDGES + e];
        s0 += a.x; s1 += a.y; s2 += a.z; s3 += a.w;
    }
    s0 += __shfl_xor(s0, 1); s0 += __shfl_xor(s0, 2);
    s1 += __shfl_xor(s1, 1); s1 += __shfl_xor(s1, 2);
    s2 += __shfl_xor(s2, 1); s2 += __shfl_xor(s2, 2);
    s3 += __shfl_xor(s3, 1); s3 += __shfl_xor(s3, 2);
    if (q == 0) {
        const float w = ev[e];
        dst[0 * E_EDGES + e] = w * s0;
        dst[1 * E_EDGES + e] = w * s1;
        dst[2 * E_EDGES + e] = w * s2;
        dst[3 * E_EDGES + e] = w * s3;
    }
}

// ============================================================================
// Kernel C: TTN Bloch contraction, SPB=4 samples/block, fp32 wave butterfly
// (double only for the final 4-wave combine + sincos). Identical to R10.
// mi[n][d] = sum_e Ri[n][e]*boT[d][e];  mo[n][d] = sum_e Ro[n][e]*biT[d][e]
// ============================================================================
__global__ __launch_bounds__(256) void k_sim(const float* __restrict__ Ri,
                                             const float* __restrict__ Ro,
                                             const float* __restrict__ X,
                                             const float* __restrict__ th,
                                             const float* __restrict__ boT,
                                             const float* __restrict__ biT,
                                             float* __restrict__ out) {
    __shared__ float  redM[4][SPB][8];
    __shared__ float  R[22][9];     // gate g (theta offset 3g) -> 3x3 Bloch rot
    __shared__ float  sM[SPB][12], cM[SPB][12];

    const int n0   = blockIdx.x * SPB;
    const int t    = threadIdx.x;   // 0..255
    const int lane = t & 63;
    const int wv   = t >> 6;

    // ---- Bloch rotation matrices for all 22 live u3 gates (t < 22) ----
    if (t < 22) {
        float T = th[3 * t], P = th[3 * t + 1], L = th[3 * t + 2];
        float st, ct, sp, cp, sl, cl;
        sincosf(T, &st, &ct);
        sincosf(P, &sp, &cp);
        sincosf(L, &sl, &cl);
        R[t][0] =  cp * ct * cl - sp * sl;
        R[t][1] = -cp * ct * sl - sp * cl;
        R[t][2] =  cp * st;
        R[t][3] =  sp * ct * cl + cp * sl;
        R[t][4] = -sp * ct * sl + cp * cl;
        R[t][5] =  sp * st;
        R[t][6] = -st * cl;
        R[t][7] =  st * sl;
        R[t][8] =  ct;
    }

    // ---- per-thread fp32 partials of mi/mo for SPB samples (coalesced) ----
    float accf[SPB][8];
#pragma unroll
    for (int s = 0; s < SPB; ++s)
#pragma unroll
        for (int j = 0; j < 8; ++j) accf[s][j] = 0.f;

    const float4* Ri4s[SPB];
    const float4* Ro4s[SPB];
#pragma unroll
    for (int s = 0; s < SPB; ++s) {
        Ri4s[s] = reinterpret_cast<const float4*>(Ri + (size_t)(n0 + s) * E_EDGES);
        Ro4s[s] = reinterpret_cast<const float4*>(Ro + (size_t)(n0 + s) * E_EDGES);
    }
    const float4* BO0 = reinterpret_cast<const float4*>(boT);
    const float4* BO1 = reinterpret_cast<const float4*>(boT + E_EDGES);
    const float4* BO2 = reinterpret_cast<const float4*>(boT + 2 * E_EDGES);
    const float4* BO3 = reinterpret_cast<const float4*>(boT + 3 * E_EDGES);
    const float4* BI0 = reinterpret_cast<const float4*>(biT);
    const float4* BI1 = reinterpret_cast<const float4*>(biT + E_EDGES);
    const float4* BI2 = reinterpret_cast<const float4*>(biT + 2 * E_EDGES);
    const float4* BI3 = reinterpret_cast<const float4*>(biT + 3 * E_EDGES);

#pragma unroll
    for (int k = 0; k < 4; ++k) {
        const int v = t + 256 * k;
        const float4 o0 = BO0[v], o1 = BO1[v], o2 = BO2[v], o3 = BO3[v];
        const float4 i0 = BI0[v], i1 = BI1[v], i2 = BI2[v], i3 = BI3[v];
#pragma unroll
        for (int s = 0; s < SPB; ++s) {
            const float4 ri = Ri4s[s][v];
            const float4 ro = Ro4s[s][v];
            accf[s][0] += ri.x * o0.x + ri.y * o0.y + ri.z * o0.z + ri.w * o0.w;
            accf[s][1] += ri.x * o1.x + ri.y * o1.y + ri.z * o1.z + ri.w * o1.w;
            accf[s][2] += ri.x * o2.x + ri.y * o2.y + ri.z * o2.z + ri.w * o2.w;
            accf[s][3] += ri.x * o3.x + ri.y * o3.y + ri.z * o3.z + ri.w * o3.w;
            accf[s][4] += ro.x * i0.x + ro.y * i0.y + ro.z * i0.z + ro.w * i0.w;
            accf[s][5] += ro.x * i1.x + ro.y * i1.y + ro.z * i1.z + ro.w * i1.w;
            accf[s][6] += ro.x * i2.x + ro.y * i2.y + ro.z * i2.z + ro.w * i2.w;
            accf[s][7] += ro.x * i3.x + ro.y * i3.y + ro.z * i3.z + ro.w * i3.w;
        }
    }

    // in-wave butterfly reduce in fp32; double only for final combine + sincos
#pragma unroll
    for (int off = 32; off >= 1; off >>= 1)
#pragma unroll
        for (int s = 0; s < SPB; ++s)
#pragma unroll
            for (int j = 0; j < 8; ++j)
                accf[s][j] += __shfl_xor(accf[s][j], off);
    if (lane == 0)
#pragma unroll
        for (int s = 0; s < SPB; ++s)
#pragma unroll
            for (int j = 0; j < 8; ++j) redM[wv][s][j] = accf[s][j];
    __syncthreads();

    // ---- M angles: double sincos, threads 0..47 -> (sample, wire) ----
    if (t < 12 * SPB) {
        const int s = t / 12, w = t % 12;
        double Mw = (w < 8)
            ? ((double)redM[0][s][w] + (double)redM[1][s][w] +
               (double)redM[2][s][w] + (double)redM[3][s][w])
            : (double)X[(n0 + s) * 4 + (w - 8)];
        double sv, cv;
        sincos(Mw, &sv, &cv);   // double: M can be O(1000) rad
        sM[s][w] = (float)sv; cM[s][w] = (float)cv;
    }
    __syncthreads();

    // ---- TTN Bloch-vector contraction: thread s handles sample s ----
    if (t < SPB) {
        const float* sMv = sM[t];
        const float* cMv = cM[t];
        auto iz = [&](int g) -> float {
            return R[g][6] * sMv[g] + R[g][8] * cMv[g];
        };
        auto ivec = [&](int g, float& x, float& y, float& z) {
            x = R[g][0] * sMv[g] + R[g][2] * cMv[g];
            y = R[g][3] * sMv[g] + R[g][5] * cMv[g];
            z = R[g][6] * sMv[g] + R[g][8] * cMv[g];
        };
        auto rot = [&](int g, float& x, float& y, float& z) {
            float nx = R[g][0] * x + R[g][1] * y + R[g][2] * z;
            float ny = R[g][3] * x + R[g][4] * y + R[g][5] * z;
            float nz = R[g][6] * x + R[g][7] * y + R[g][8] * z;
            x = nx; y = ny; z = nz;
        };

        const float z0  = iz(0),  z3  = iz(3), z4 = iz(4);
        const float z7  = iz(7),  z8  = iz(8), z11 = iz(11);

        float x1, y1, z1;  ivec(1, x1, y1, z1);                // w1
        y1 *= z0;  z1 *= z0;          rot(12, x1, y1, z1);     // cx(0,1), u3@36

        float x2, y2, z2;  ivec(2, x2, y2, z2);                // w2
        y2 *= z3;  z2 *= z3;          rot(13, x2, y2, z2);     // cx(3,2), u3@39
        y2 *= z1;  z2 *= z1;          rot(18, x2, y2, z2);     // cx(1,2), u3@54

        float x6, y6, z6;  ivec(6, x6, y6, z6);                // w6
        y6 *= z7;  z6 *= z7;          rot(15, x6, y6, z6);     // cx(7,6), u3@45

        float x5, y5, z5;  ivec(5, x5, y5, z5);                // w5
        y5 *= z4;  z5 *= z4;          rot(14, x5, y5, z5);     // cx(4,5), u3@42
        y5 *= z6;  z5 *= z6;          rot(19, x5, y5, z5);     // cx(6,5), u3@57
        y5 *= z2;  z5 *= z2;          rot(20, x5, y5, z5);     // cx(2,5), u3@60

        float xA, yA, zA;  ivec(10, xA, yA, zA);               // w10
        yA *= z11; zA *= z11;         rot(17, xA, yA, zA);     // cx(11,10), u3@51

        float x9, y9, z9;  ivec(9, x9, y9, z9);                // w9
        y9 *= z8;  z9 *= z8;          rot(16, x9, y9, z9);     // cx(8,9), u3@48
        y9 *= zA;  z9 *= zA;          rot(21, x9, y9, z9);     // cx(10,9), u3@63
        z9 *= z5;                                              // cx(5,9)

        out[n0 + t] = (float)(3.14159265358979323846 * (1.0 - (double)z9));
    }
}

extern "C" void kernel_launch(void* const* d_in, const int* in_sizes, int n_in,
                              void* d_out, int out_size, void* d_ws, size_t ws_size,
                              hipStream_t stream) {
    (void)in_sizes; (void)n_in; (void)out_size; (void)ws_size;
    const float* X  = (const float*)d_in[0];
    const float* ev = (const float*)d_in[1];
    const float* Ri = (const float*)d_in[2];
    const float* Ro = (const float*)d_in[3];
    const float* th = (const float*)d_in[4];
    float* out = (float*)d_out;

    float* pbo = (float*)d_ws;                              // [NSPLIT][4096][4]
    float* pbi = pbo + (size_t)NSPLIT * E_EDGES * 4;        // [NSPLIT][4096][4]
    float* boT = pbi + (size_t)NSPLIT * E_EDGES * 4;        // [4][4096]
    float* biT = boT + (size_t)4 * E_EDGES;                 // [4][4096]

    hipLaunchKernelGGL(k_partial, dim3(8, NSPLIT), dim3(256), 0, stream,
                       Ri, Ro, X, pbo, pbi);
    hipLaunchKernelGGL(k_reduce, dim3(128), dim3(256), 0, stream,
                       pbo, pbi, ev, boT, biT);
    hipLaunchKernelGGL(k_sim, dim3(N_SAMPLES / SPB), dim3(256), 0, stream,
                       Ri, Ro, X, th, boT, biT, out);
}

// Round 14
// 38.364 us; speedup vs baseline: 4.8396x; 1.1451x over previous
//
#include <hip/hip_runtime.h>
#include <math.h>

#define N_SAMPLES 2048
#define E_EDGES   4096
#define NSPLIT    64            // 32 rows per partial slice (empirical optimum)
#define SPB       4             // samples per block in k_sim

// ---------------- Kernel A: split-K partials of bo = Ro^T X, bi = Ri^T X ----
// grid (8, 64) = 512 blocks (2/CU — empirically optimal: 256 and 1024 both
// regress). Block: 128 float4-cols x 32 rows, rows split 2-way across thread
// halves, combined through padded LDS. NORMAL cache-resident stores (nt
// stores: -56% R9; atomic accumulate: -63% R12; spin-barrier fusion: -5x R11).
__global__ __launch_bounds__(256) void k_partial(const float* __restrict__ Ri,
                                                 const float* __restrict__ Ro,
                                                 const float* __restrict__ X,
                                                 float* __restrict__ pbo,
                                                 float* __restrict__ pbi) {
    __shared__ float comb[128][33];   // padded: conflict-free

    const int ec   = blockIdx.x;      // 0..7  (128 float4-col chunk)
    const int ns   = blockIdx.y;      // 0..63 (32-row chunk)
    const int t    = threadIdx.x;
    const int col  = t & 127;         // local float4 col
    const int half = t >> 7;          // 0/1 row-half
    const int v    = ec * 128 + col;  // global float4 col (0..1023)

    const float4* Ri4 = reinterpret_cast<const float4*>(Ri);
    const float4* Ro4 = reinterpret_cast<const float4*>(Ro);
    const float4* X4  = reinterpret_cast<const float4*>(X);

    float abo[4][4], abi[4][4];
#pragma unroll
    for (int c = 0; c < 4; ++c)
#pragma unroll
        for (int d = 0; d < 4; ++d) { abo[c][d] = 0.f; abi[c][d] = 0.f; }

    const int n0 = ns * 32 + half * 16;
#pragma unroll 4
    for (int n = n0; n < n0 + 16; ++n) {
        float4 xv = X4[n];
        float4 ro = Ro4[(size_t)n * 1024 + v];
        float4 ri = Ri4[(size_t)n * 1024 + v];
        float xs[4]  = {xv.x, xv.y, xv.z, xv.w};
        float ros[4] = {ro.x, ro.y, ro.z, ro.w};
        float ris[4] = {ri.x, ri.y, ri.z, ri.w};
#pragma unroll
        for (int c = 0; c < 4; ++c)
#pragma unroll
            for (int d = 0; d < 4; ++d) {
                abo[c][d] += ros[c] * xs[d];
                abi[c][d] += ris[c] * xs[d];
            }
    }

    if (half) {
#pragma unroll
        for (int c = 0; c < 4; ++c)
#pragma unroll
            for (int d = 0; d < 4; ++d) {
                comb[col][c * 4 + d]      = abo[c][d];
                comb[col][16 + c * 4 + d] = abi[c][d];
            }
    }
    __syncthreads();
    if (!half) {
        float4* pbo4 = reinterpret_cast<float4*>(pbo);
        float4* pbi4 = reinterpret_cast<float4*>(pbi);
#pragma unroll
        for (int c = 0; c < 4; ++c) {
#pragma unroll
            for (int d = 0; d < 4; ++d) {
                abo[c][d] += comb[col][c * 4 + d];
                abi[c][d] += comb[col][16 + c * 4 + d];
            }
            size_t idx = (size_t)ns * E_EDGES + 4 * (size_t)v + c;
            pbo4[idx] = make_float4(abo[c][0], abo[c][1], abo[c][2], abo[c][3]);
            pbi4[idx] = make_float4(abi[c][0], abi[c][1], abi[c][2], abi[c][3]);
        }
    }
}

// ---------------- Kernel B: reduce partials -> boT, biT (d-major, e-folded) -
// boT[d][e] = e[e] * bo[e][d].  4-way ns-split per (mat,e): thread (mat,e,q)
// sums 16 slices; 2-step shfl_xor combine; q==0 lane writes.
// grid: 2 mats * 4096 e * 4 q / 256 = 128 blocks.
__global__ __launch_bounds__(256) void k_reduce(const float* __restrict__ pbo,
                                                const float* __restrict__ pbi,
                                                const float* __restrict__ ev,
                                                float* __restrict__ boT,
                                                float* __restrict__ biT) {
    const int gid = blockIdx.x * 256 + threadIdx.x;   // 0..32767
    const int q   = gid & 3;
    const int e   = (gid >> 2) & 4095;
    const int mat = gid >> 14;                        // 0 = bo, 1 = bi
    const float4* src = reinterpret_cast<const float4*>(mat ? pbi : pbo);
    float*        dst = mat ? biT : boT;

    float s0 = 0.f, s1 = 0.f, s2 = 0.f, s3 = 0.f;
#pragma unroll 4
    for (int ns = q * 16; ns < q * 16 + 16; ++ns) {
        float4 a = src[(size_t)ns * E_EDGES + e];
        s0 += a.x; s1 += a.y; s2 += a.z; s3 += a.w;
    }
    s0 += __shfl_xor(s0, 1); s0 += __shfl_xor(s0, 2);
    s1 += __shfl_xor(s1, 1); s1 += __shfl_xor(s1, 2);
    s2 += __shfl_xor(s2, 1); s2 += __shfl_xor(s2, 2);
    s3 += __shfl_xor(s3, 1); s3 += __shfl_xor(s3, 2);
    if (q == 0) {
        const float w = ev[e];
        dst[0 * E_EDGES + e] = w * s0;
        dst[1 * E_EDGES + e] = w * s1;
        dst[2 * E_EDGES + e] = w * s2;
        dst[3 * E_EDGES + e] = w * s3;
    }
}

// ============================================================================
// Kernel C: TTN Bloch contraction, SPB=4 samples/block, fp32 wave butterfly
// (double only for the final 4-wave combine + sincos). Amortizes boT/biT L2
// reads 4x (268 MB -> 67 MB).
// mi[n][d] = sum_e Ri[n][e]*boT[d][e];  mo[n][d] = sum_e Ro[n][e]*biT[d][e]
// ============================================================================
__global__ __launch_bounds__(256) void k_sim(const float* __restrict__ Ri,
                                             const float* __restrict__ Ro,
                                             const float* __restrict__ X,
                                             const float* __restrict__ th,
                                             const float* __restrict__ boT,
                                             const float* __restrict__ biT,
                                             float* __restrict__ out) {
    __shared__ float  redM[4][SPB][8];
    __shared__ float  R[22][9];     // gate g (theta offset 3g) -> 3x3 Bloch rot
    __shared__ float  sM[SPB][12], cM[SPB][12];

    const int n0   = blockIdx.x * SPB;
    const int t    = threadIdx.x;   // 0..255
    const int lane = t & 63;
    const int wv   = t >> 6;

    // ---- Bloch rotation matrices for all 22 live u3 gates (t < 22) ----
    if (t < 22) {
        float T = th[3 * t], P = th[3 * t + 1], L = th[3 * t + 2];
        float st, ct, sp, cp, sl, cl;
        sincosf(T, &st, &ct);
        sincosf(P, &sp, &cp);
        sincosf(L, &sl, &cl);
        R[t][0] =  cp * ct * cl - sp * sl;
        R[t][1] = -cp * ct * sl - sp * cl;
        R[t][2] =  cp * st;
        R[t][3] =  sp * ct * cl + cp * sl;
        R[t][4] = -sp * ct * sl + cp * cl;
        R[t][5] =  sp * st;
        R[t][6] = -st * cl;
        R[t][7] =  st * sl;
        R[t][8] =  ct;
    }

    // ---- per-thread fp32 partials of mi/mo for SPB samples (coalesced) ----
    float accf[SPB][8];
#pragma unroll
    for (int s = 0; s < SPB; ++s)
#pragma unroll
        for (int j = 0; j < 8; ++j) accf[s][j] = 0.f;

    const float4* Ri4s[SPB];
    const float4* Ro4s[SPB];
#pragma unroll
    for (int s = 0; s < SPB; ++s) {
        Ri4s[s] = reinterpret_cast<const float4*>(Ri + (size_t)(n0 + s) * E_EDGES);
        Ro4s[s] = reinterpret_cast<const float4*>(Ro + (size_t)(n0 + s) * E_EDGES);
    }
    const float4* BO0 = reinterpret_cast<const float4*>(boT);
    const float4* BO1 = reinterpret_cast<const float4*>(boT + E_EDGES);
    const float4* BO2 = reinterpret_cast<const float4*>(boT + 2 * E_EDGES);
    const float4* BO3 = reinterpret_cast<const float4*>(boT + 3 * E_EDGES);
    const float4* BI0 = reinterpret_cast<const float4*>(biT);
    const float4* BI1 = reinterpret_cast<const float4*>(biT + E_EDGES);
    const float4* BI2 = reinterpret_cast<const float4*>(biT + 2 * E_EDGES);
    const float4* BI3 = reinterpret_cast<const float4*>(biT + 3 * E_EDGES);

#pragma unroll
    for (int k = 0; k < 4; ++k) {
        const int v = t + 256 * k;
        const float4 o0 = BO0[v], o1 = BO1[v], o2 = BO2[v], o3 = BO3[v];
        const float4 i0 = BI0[v], i1 = BI1[v], i2 = BI2[v], i3 = BI3[v];
#pragma unroll
        for (int s = 0; s < SPB; ++s) {
            const float4 ri = Ri4s[s][v];
            const float4 ro = Ro4s[s][v];
            accf[s][0] += ri.x * o0.x + ri.y * o0.y + ri.z * o0.z + ri.w * o0.w;
            accf[s][1] += ri.x * o1.x + ri.y * o1.y + ri.z * o1.z + ri.w * o1.w;
            accf[s][2] += ri.x * o2.x + ri.y * o2.y + ri.z * o2.z + ri.w * o2.w;
            accf[s][3] += ri.x * o3.x + ri.y * o3.y + ri.z * o3.z + ri.w * o3.w;
            accf[s][4] += ro.x * i0.x + ro.y * i0.y + ro.z * i0.z + ro.w * i0.w;
            accf[s][5] += ro.x * i1.x + ro.y * i1.y + ro.z * i1.z + ro.w * i1.w;
            accf[s][6] += ro.x * i2.x + ro.y * i2.y + ro.z * i2.z + ro.w * i2.w;
            accf[s][7] += ro.x * i3.x + ro.y * i3.y + ro.z * i3.z + ro.w * i3.w;
        }
    }

    // in-wave butterfly reduce in fp32; double only for final combine + sincos
#pragma unroll
    for (int off = 32; off >= 1; off >>= 1)
#pragma unroll
        for (int s = 0; s < SPB; ++s)
#pragma unroll
            for (int j = 0; j < 8; ++j)
                accf[s][j] += __shfl_xor(accf[s][j], off);
    if (lane == 0)
#pragma unroll
        for (int s = 0; s < SPB; ++s)
#pragma unroll
            for (int j = 0; j < 8; ++j) redM[wv][s][j] = accf[s][j];
    __syncthreads();

    // ---- M angles: double sincos, threads 0..47 -> (sample, wire) ----
    if (t < 12 * SPB) {
        const int s = t / 12, w = t % 12;
        double Mw = (w < 8)
            ? ((double)redM[0][s][w] + (double)redM[1][s][w] +
               (double)redM[2][s][w] + (double)redM[3][s][w])
            : (double)X[(n0 + s) * 4 + (w - 8)];
        double sv, cv;
        sincos(Mw, &sv, &cv);   // double: M can be O(1000) rad
        sM[s][w] = (float)sv; cM[s][w] = (float)cv;
    }
    __syncthreads();

    // ---- TTN Bloch-vector contraction: thread s handles sample s ----
    if (t < SPB) {
        const float* sMv = sM[t];
        const float* cMv = cM[t];
        auto iz = [&](int g) -> float {
            return R[g][6] * sMv[g] + R[g][8] * cMv[g];
        };
        auto ivec = [&](int g, float& x, float& y, float& z) {
            x = R[g][0] * sMv[g] + R[g][2] * cMv[g];
            y = R[g][3] * sMv[g] + R[g][5] * cMv[g];
            z = R[g][6] * sMv[g] + R[g][8] * cMv[g];
        };
        auto rot = [&](int g, float& x, float& y, float& z) {
            float nx = R[g][0] * x + R[g][1] * y + R[g][2] * z;
            float ny = R[g][3] * x + R[g][4] * y + R[g][5] * z;
            float nz = R[g][6] * x + R[g][7] * y + R[g][8] * z;
            x = nx; y = ny; z = nz;
        };

        const float z0  = iz(0),  z3  = iz(3), z4 = iz(4);
        const float z7  = iz(7),  z8  = iz(8), z11 = iz(11);

        float x1, y1, z1;  ivec(1, x1, y1, z1);                // w1
        y1 *= z0;  z1 *= z0;          rot(12, x1, y1, z1);     // cx(0,1), u3@36

        float x2, y2, z2;  ivec(2, x2, y2, z2);                // w2
        y2 *= z3;  z2 *= z3;          rot(13, x2, y2, z2);     // cx(3,2), u3@39
        y2 *= z1;  z2 *= z1;          rot(18, x2, y2, z2);     // cx(1,2), u3@54

        float x6, y6, z6;  ivec(6, x6, y6, z6);                // w6
        y6 *= z7;  z6 *= z7;          rot(15, x6, y6, z6);     // cx(7,6), u3@45

        float x5, y5, z5;  ivec(5, x5, y5, z5);                // w5
        y5 *= z4;  z5 *= z4;          rot(14, x5, y5, z5);     // cx(4,5), u3@42
        y5 *= z6;  z5 *= z6;          rot(19, x5, y5, z5);     // cx(6,5), u3@57
        y5 *= z2;  z5 *= z2;          rot(20, x5, y5, z5);     // cx(2,5), u3@60

        float xA, yA, zA;  ivec(10, xA, yA, zA);               // w10
        yA *= z11; zA *= z11;         rot(17, xA, yA, zA);     // cx(11,10), u3@51

        float x9, y9, z9;  ivec(9, x9, y9, z9);                // w9
        y9 *= z8;  z9 *= z8;          rot(16, x9, y9, z9);     // cx(8,9), u3@48
        y9 *= zA;  z9 *= zA;          rot(21, x9, y9, z9);     // cx(10,9), u3@63
        z9 *= z5;                                              // cx(5,9)

        out[n0 + t] = (float)(3.14159265358979323846 * (1.0 - (double)z9));
    }
}

extern "C" void kernel_launch(void* const* d_in, const int* in_sizes, int n_in,
                              void* d_out, int out_size, void* d_ws, size_t ws_size,
                              hipStream_t stream) {
    (void)in_sizes; (void)n_in; (void)out_size; (void)ws_size;
    const float* X  = (const float*)d_in[0];
    const float* ev = (const float*)d_in[1];
    const float* Ri = (const float*)d_in[2];
    const float* Ro = (const float*)d_in[3];
    const float* th = (const float*)d_in[4];
    float* out = (float*)d_out;

    float* pbo = (float*)d_ws;                              // [NSPLIT][4096][4]
    float* pbi = pbo + (size_t)NSPLIT * E_EDGES * 4;        // [NSPLIT][4096][4]
    float* boT = pbi + (size_t)NSPLIT * E_EDGES * 4;        // [4][4096]
    float* biT = boT + (size_t)4 * E_EDGES;                 // [4][4096]

    hipLaunchKernelGGL(k_partial, dim3(8, NSPLIT), dim3(256), 0, stream,
                       Ri, Ro, X, pbo, pbi);
    hipLaunchKernelGGL(k_reduce, dim3(128), dim3(256), 0, stream,
                       pbo, pbi, ev, boT, biT);
    hipLaunchKernelGGL(k_sim, dim3(N_SAMPLES / SPB), dim3(256), 0, stream,
                       Ri, Ro, X, th, boT, biT, out);
}